// Round 17
// baseline (73.455 us; speedup 1.0000x reference)
//
#include <hip/hip_runtime.h>
#include <math.h>

#define BN 16
#define LC 2048
#define LQ 256
#define DD 256
#define BM 128
#define NT 512

typedef _Float16 half8 __attribute__((ext_vector_type(8)));
typedef float f32x16 __attribute__((ext_vector_type(16)));
typedef float f32x4 __attribute__((ext_vector_type(4)));

typedef const __attribute__((address_space(1))) void* gas_p;
typedef __attribute__((address_space(3))) void* lds_p;
#define GLOAD_LDS16(gp, lp) \
    __builtin_amdgcn_global_load_lds((gas_p)(gp), (lds_p)(lp), 16, 0, 0)

__device__ __forceinline__ float waveReduceSum(float v) {
#pragma unroll
    for (int o = 32; o > 0; o >>= 1) v += __shfl_xor(v, o, 64);
    return v;
}
__device__ __forceinline__ float waveReduceMax(float v) {
#pragma unroll
    for (int o = 32; o > 0; o >>= 1) v = fmaxf(v, __shfl_xor(v, o, 64));
    return v;
}

// Prep: Qh = fp16(Q), QTh = fp16(Q^T), cq[n][q] = Q . w_q
__global__ __launch_bounds__(256) void k_prep(const float* __restrict__ q,
                                              const float* __restrict__ W,
                                              _Float16* __restrict__ Qh,
                                              _Float16* __restrict__ QTh,
                                              float* __restrict__ cq) {
    __shared__ float tile[32][257];
    const int n = blockIdx.y;
    const int q0 = blockIdx.x * 32;
    const int t = threadIdx.x;

#pragma unroll
    for (int i = 0; i < 32; ++i) {
        const float v = q[((size_t)(n * LQ + q0 + i)) * DD + t];
        Qh[((size_t)(n * LQ + q0 + i)) * DD + t] = (_Float16)v;
        tile[i][t] = v;
    }
    __syncthreads();

    {
        const int row = t >> 3, sub = t & 7;
        float s = 0.f;
#pragma unroll
        for (int j = 0; j < 32; ++j)
            s = fmaf(tile[row][sub * 32 + j], W[DD + sub * 32 + j], s);
        s += __shfl_xor(s, 1, 64);
        s += __shfl_xor(s, 2, 64);
        s += __shfl_xor(s, 4, 64);
        if (sub == 0) cq[n * LQ + q0 + row] = s;
    }

    const int tx = t & 31, ty = t >> 5;
#pragma unroll
    for (int db = 0; db < 8; ++db) {
#pragma unroll
        for (int i = 0; i < 4; ++i) {
            const int d = db * 32 + ty + 8 * i;
            QTh[((size_t)(n * DD + d)) * LQ + q0 + tx] = (_Float16)tile[tx][d];
        }
    }
}

// Fused MFMA kernel (r12 base): XCD swizzle + NT output stores.
// Change vs r12: G part 0 (ctx copy) written DURING A-stage with NT stores,
// spreading the write burst; epilogue writes only parts 1,2.
__global__ __launch_bounds__(NT) void k_main(const float* __restrict__ ctx,
                                             const _Float16* __restrict__ Qh,
                                             const _Float16* __restrict__ QTh,
                                             const float* __restrict__ cq,
                                             const float* __restrict__ W,
                                             float* __restrict__ out,
                                             float* __restrict__ pq,
                                             float* __restrict__ KS) {
    __shared__ _Float16 Abuf[BM * 256];     // 64KB, 512B rows, XOR-swizzled
    __shared__ _Float16 Bbuf[2][256 * 64];  // 2 x 32KB, 128B rows, XOR-swizzled
    __shared__ float rowterm[BM];
    __shared__ float m_lds[BM];
    __shared__ float linv_lds[BM];
    __shared__ float eexp[BM];
    __shared__ float redmax[4][BM];
    __shared__ float redsum[4][BM];

    const int t = threadIdx.x;
    const int lane = t & 63, wid = t >> 6;
    const int l31 = lane & 31, lh = lane >> 5;
    const int wr = wid >> 2, wc = wid & 3;
    // XCD-chunked bijective swizzle: each XCD owns 2 whole batches.
    const int bx = blockIdx.x;
    const int blk = (bx & 7) * 32 + (bx >> 3);
    const int n = blk >> 4;   // 16 blocks per batch
    const int blk16 = blk & 15;
    const int c0 = blk16 * BM;

    const _Float16* Qhn = Qh + (size_t)n * LQ * DD;
    const _Float16* QThn = QTh + (size_t)n * DD * LQ;

    auto stageB = [&](int kc, const _Float16* src, int buf) {
#pragma unroll
        for (int j = 0; j < 4; ++j) {
            const int r = wid * 32 + j * 8 + (lane >> 3);
            const int gs = (lane & 7) ^ (r & 7);
            const _Float16* gp = src + (size_t)r * 256 + kc * 64 + gs * 8;
            _Float16* lp = &Bbuf[buf][(wid * 32 + j * 8) * 64];
            GLOAD_LDS16(gp, lp);
        }
    };

    auto gemmChunk = [&](f32x16 (&acc)[2][2], int kcA, int buf) {
#pragma unroll
        for (int kk = 0; kk < 4; ++kk) {
            half8 af[2], bf[2];
#pragma unroll
            for (int mt = 0; mt < 2; ++mt) {
                const int row = 64 * wr + 32 * mt + l31;
                const int kb = kcA * 128 + 32 * kk + 16 * lh;
                af[mt] = *(const half8*)((const char*)Abuf + row * 512 + (kb ^ ((row & 7) << 4)));
            }
#pragma unroll
            for (int nt = 0; nt < 2; ++nt) {
                const int row = 64 * wc + 32 * nt + l31;
                const int kb = 32 * kk + 16 * lh;
                bf[nt] = *(const half8*)((const char*)Bbuf[buf] + row * 128 + (kb ^ ((row & 7) << 4)));
            }
#pragma unroll
            for (int mt = 0; mt < 2; ++mt)
#pragma unroll
                for (int nt = 0; nt < 2; ++nt)
                    acc[mt][nt] = __builtin_amdgcn_mfma_f32_32x32x16_f16(af[mt], bf[nt], acc[mt][nt], 0, 0, 0);
        }
    };

    stageB(0, Qhn, 0);  // async, in flight under A-stage

    // Stage A = ctx*w_m (fp16, swizzled) + rowterm = ctx.w_c + NT-write part 0
    {
        const int g = t & 31;
        const int r0 = t >> 5;
        float wmv[8], wcv[8];
#pragma unroll
        for (int j = 0; j < 8; ++j) {
            wmv[j] = W[2 * DD + g * 8 + j];
            wcv[j] = W[g * 8 + j];
        }
#pragma unroll
        for (int i = 0; i < 8; ++i) {
            const int r = r0 + 16 * i;
            const size_t gc = (size_t)(n * LC + c0 + r);
            const float* srcr = ctx + gc * DD + g * 8;
            const float4 aa = *(const float4*)srcr;
            const float4 bb = *(const float4*)(srcr + 4);
            const float vals[8] = {aa.x, aa.y, aa.z, aa.w, bb.x, bb.y, bb.z, bb.w};
            // G part 0 = ctx, NT stores (no L2 pressure on the staging path)
            float* dstr = out + gc * 1024 + g * 8;
#pragma unroll
            for (int j = 0; j < 8; ++j) __builtin_nontemporal_store(vals[j], &dstr[j]);
            half8 cmv;
            float rt = 0.f;
#pragma unroll
            for (int j = 0; j < 8; ++j) {
                cmv[j] = (_Float16)(vals[j] * wmv[j]);
                rt = fmaf(vals[j], wcv[j], rt);
            }
            *(half8*)((char*)Abuf + r * 512 + ((g * 16) ^ ((r & 7) << 4))) = cmv;
#pragma unroll
            for (int o = 16; o > 0; o >>= 1) rt += __shfl_xor(rt, o, 64);
            if (g == 0) rowterm[r] = rt;
        }
    }
    __syncthreads();  // A + B0 ready

    // GEMM1: S = CM @ Q^T
    f32x16 acc[2][2] = {};
#pragma unroll
    for (int kc = 0; kc < 4; ++kc) {
        if (kc) __syncthreads();
        if (kc < 3) stageB(kc + 1, Qhn, (kc + 1) & 1);
        else stageB(0, QThn, 0);  // prefetch GEMM2 chunk 0
        gemmChunk(acc, kc, kc & 1);
    }
    __syncthreads();  // S1

    float cqv[2];
    cqv[0] = cq[n * LQ + 64 * wc + l31];
    cqv[1] = cq[n * LQ + 64 * wc + 32 + l31];

    // s = acc + rowterm + cq; per-row max
#pragma unroll
    for (int mt = 0; mt < 2; ++mt) {
#pragma unroll
        for (int r = 0; r < 16; ++r) {
            const int rl = 64 * wr + 32 * mt + (r & 3) + 8 * (r >> 2) + 4 * lh;
            const float rterm = rowterm[rl];
            const float v0 = acc[mt][0][r] + rterm + cqv[0];
            const float v1 = acc[mt][1][r] + rterm + cqv[1];
            acc[mt][0][r] = v0;
            acc[mt][1][r] = v1;
            float mx = fmaxf(v0, v1);
#pragma unroll
            for (int o = 16; o > 0; o >>= 1) mx = fmaxf(mx, __shfl_xor(mx, o, 64));
            if (l31 == 0) redmax[wc][rl] = mx;
        }
    }
    __syncthreads();  // S2
    if (t < BM)
        m_lds[t] = fmaxf(fmaxf(redmax[0][t], redmax[1][t]), fmaxf(redmax[2][t], redmax[3][t]));
    __syncthreads();  // S3

    // waves 0,1: per-64-row q2c partial stats
    if (t < BM) {
        const float mv = m_lds[t];
        const float kb = waveReduceMax(mv);
        const float e = __expf(mv - kb);
        eexp[t] = e;
        const float sb = waveReduceSum(e);
        if (lane == 0) {
            KS[(n * 32 + blk16 * 2 + (t >> 6)) * 2 + 0] = kb;
            KS[(n * 32 + blk16 * 2 + (t >> 6)) * 2 + 1] = sb;
        }
    }

    // p = exp(s - m); row sums; store P (unnormalized fp16) into Abuf
#pragma unroll
    for (int mt = 0; mt < 2; ++mt) {
#pragma unroll
        for (int r = 0; r < 16; ++r) {
            const int rl = 64 * wr + 32 * mt + (r & 3) + 8 * (r >> 2) + 4 * lh;
            const float mrow = m_lds[rl];
            const float p0 = __expf(acc[mt][0][r] - mrow);
            const float p1 = __expf(acc[mt][1][r] - mrow);
            const int q0 = 64 * wc + l31, q1 = q0 + 32;
            *((_Float16*)((char*)Abuf + rl * 512 + ((q0 * 2) ^ ((rl & 7) << 4)))) = (_Float16)p0;
            *((_Float16*)((char*)Abuf + rl * 512 + ((q1 * 2) ^ ((rl & 7) << 4)))) = (_Float16)p1;
            float sm = p0 + p1;
#pragma unroll
            for (int o = 16; o > 0; o >>= 1) sm += __shfl_xor(sm, o, 64);
            if (l31 == 0) redsum[wc][rl] = sm;
        }
    }
    __syncthreads();  // S4
    if (t < BM)
        linv_lds[t] = 1.0f / (redsum[0][t] + redsum[1][t] + redsum[2][t] + redsum[3][t]);
    __syncthreads();  // S5

    // GEMM2: c2q = P @ Q
    f32x16 acc2[2][2] = {};
#pragma unroll
    for (int kc = 0; kc < 4; ++kc) {
        if (kc) __syncthreads();
        if (kc < 3) stageB(kc + 1, QThn, (kc + 1) & 1);
        gemmChunk(acc2, kc, kc & 1);
    }

    // epilogue: G parts 1,2 (non-temporal) + q2c partial accumulation
    float pqa[2] = {0.f, 0.f};
#pragma unroll
    for (int mt = 0; mt < 2; ++mt) {
#pragma unroll
        for (int nt = 0; nt < 2; ++nt) {
            const int col = 64 * wc + 32 * nt + l31;
#pragma unroll
            for (int r = 0; r < 16; ++r) {
                const int rl = 64 * wr + 32 * mt + (r & 3) + 8 * (r >> 2) + 4 * lh;
                const size_t gc = (size_t)(n * LC + c0 + rl);
                const float li = linv_lds[rl];
                const float cv = ctx[gc * DD + col];
                const float ov = acc2[mt][nt][r] * li;
                const size_t ob = gc * 1024 + col;
                __builtin_nontemporal_store(ov, &out[ob + 256]);
                __builtin_nontemporal_store(cv * ov, &out[ob + 512]);
                pqa[nt] = fmaf(eexp[rl], cv, pqa[nt]);
            }
        }
    }
#pragma unroll
    for (int nt = 0; nt < 2; ++nt) {
        pqa[nt] += __shfl_xor(pqa[nt], 32, 64);
        if (lh == 0) {
            const int col = 64 * wc + 32 * nt + l31;
            pq[((size_t)(n * 32 + blk16 * 2 + wr)) * 256 + col] = pqa[nt];
        }
    }
}

// Tail: combine per-batch partials -> q2c (float4 per thread), write part 3.
__global__ __launch_bounds__(256) void k_tail(const float* __restrict__ ctx,
                                              const float* __restrict__ pq,
                                              const float* __restrict__ KS,
                                              float* __restrict__ out) {
    // XCD-chunked swizzle aligned with k_main's batch->XCD mapping.
    const int bx = blockIdx.x;
    const int blk = (bx & 7) * 64 + (bx >> 3);
    const int n = blk >> 5;
    const int c0 = (blk & 31) * 64;
    const int t = threadIdx.x;
    const int cg = t & 63;   // cols 4cg..4cg+3
    const int rs = t >> 6;   // rows rs*16..rs*16+15

    float bmax = -1e30f;
#pragma unroll
    for (int b = 0; b < 32; ++b) bmax = fmaxf(bmax, KS[(n * 32 + b) * 2]);
    float Z = 0.f;
    float4 a = {0.f, 0.f, 0.f, 0.f};
#pragma unroll
    for (int b = 0; b < 32; ++b) {
        const float w = __expf(KS[(n * 32 + b) * 2] - bmax);
        Z = fmaf(w, KS[(n * 32 + b) * 2 + 1], Z);
        const float4 p4 = *(const float4*)&pq[((size_t)(n * 32 + b)) * 256 + cg * 4];
        a.x = fmaf(w, p4.x, a.x);
        a.y = fmaf(w, p4.y, a.y);
        a.z = fmaf(w, p4.z, a.z);
        a.w = fmaf(w, p4.w, a.w);
    }
    const float zi = 1.0f / Z;
    const float4 q2c4 = {a.x * zi, a.y * zi, a.z * zi, a.w * zi};

#pragma unroll
    for (int r = 0; r < 16; ++r) {
        const size_t gc = (size_t)(n * LC + c0 + rs * 16 + r);
        const float4 cv = *(const float4*)&ctx[gc * DD + cg * 4];
        f32x4 ov;
        ov.x = cv.x * q2c4.x;
        ov.y = cv.y * q2c4.y;
        ov.z = cv.z * q2c4.z;
        ov.w = cv.w * q2c4.w;
        __builtin_nontemporal_store(ov, (f32x4*)&out[gc * 1024 + 768 + cg * 4]);
    }
}

extern "C" void kernel_launch(void* const* d_in, const int* in_sizes, int n_in,
                              void* d_out, int out_size, void* d_ws, size_t ws_size,
                              hipStream_t stream) {
    const float* ctx = (const float*)d_in[0];  // (16,2048,256)
    const float* q = (const float*)d_in[1];    // (16,256,256)
    const float* W = (const float*)d_in[2];    // (768,)
    float* out = (float*)d_out;                // (16,2048,1024)

    _Float16* Qh = (_Float16*)d_ws;                    // 2 MB
    _Float16* QTh = Qh + (size_t)BN * LQ * DD;         // 2 MB
    float* fws = (float*)(QTh + (size_t)BN * DD * LQ);
    float* cq = fws;                  // 4096
    float* pq = cq + BN * LQ;         // 16*32*256 = 131072
    float* KS = pq + BN * 32 * 256;   // 1024

    k_prep<<<dim3(LQ / 32, BN), 256, 0, stream>>>(q, W, Qh, QTh, cq);
    k_main<<<BN * LC / BM, NT, 0, stream>>>(ctx, Qh, QTh, cq, W, out, pq, KS);
    k_tail<<<BN * LC / 64, 256, 0, stream>>>(ctx, pq, KS, out);
}

// Round 18
// 65.987 us; speedup vs baseline: 1.1132x; 1.1132x over previous
//
#include <hip/hip_runtime.h>
#include <math.h>

#define BN 16
#define LC 2048
#define LQ 256
#define DD 256
#define BM 128
#define NT 512

typedef _Float16 half8 __attribute__((ext_vector_type(8)));
typedef float f32x16 __attribute__((ext_vector_type(16)));
typedef float f32x4 __attribute__((ext_vector_type(4)));

typedef const __attribute__((address_space(1))) void* gas_p;
typedef __attribute__((address_space(3))) void* lds_p;
#define GLOAD_LDS16(gp, lp) \
    __builtin_amdgcn_global_load_lds((gas_p)(gp), (lds_p)(lp), 16, 0, 0)

__device__ __forceinline__ float waveReduceSum(float v) {
#pragma unroll
    for (int o = 32; o > 0; o >>= 1) v += __shfl_xor(v, o, 64);
    return v;
}
__device__ __forceinline__ float waveReduceMax(float v) {
#pragma unroll
    for (int o = 32; o > 0; o >>= 1) v = fmaxf(v, __shfl_xor(v, o, 64));
    return v;
}

// Prep: Qh = fp16(Q), QTh = fp16(Q^T), cq[n][q] = Q . w_q
__global__ __launch_bounds__(256) void k_prep(const float* __restrict__ q,
                                              const float* __restrict__ W,
                                              _Float16* __restrict__ Qh,
                                              _Float16* __restrict__ QTh,
                                              float* __restrict__ cq) {
    __shared__ float tile[32][257];
    const int n = blockIdx.y;
    const int q0 = blockIdx.x * 32;
    const int t = threadIdx.x;

#pragma unroll
    for (int i = 0; i < 32; ++i) {
        const float v = q[((size_t)(n * LQ + q0 + i)) * DD + t];
        Qh[((size_t)(n * LQ + q0 + i)) * DD + t] = (_Float16)v;
        tile[i][t] = v;
    }
    __syncthreads();

    {
        const int row = t >> 3, sub = t & 7;
        float s = 0.f;
#pragma unroll
        for (int j = 0; j < 32; ++j)
            s = fmaf(tile[row][sub * 32 + j], W[DD + sub * 32 + j], s);
        s += __shfl_xor(s, 1, 64);
        s += __shfl_xor(s, 2, 64);
        s += __shfl_xor(s, 4, 64);
        if (sub == 0) cq[n * LQ + q0 + row] = s;
    }

    const int tx = t & 31, ty = t >> 5;
#pragma unroll
    for (int db = 0; db < 8; ++db) {
#pragma unroll
        for (int i = 0; i < 4; ++i) {
            const int d = db * 32 + ty + 8 * i;
            QTh[((size_t)(n * DD + d)) * LQ + q0 + tx] = (_Float16)tile[tx][d];
        }
    }
}

// Fused MFMA kernel (r12/r16 base): XCD swizzle + NT output stores.
// Change: epilogue writes only parts 1,2 (part 0 moved to k_tail).
__global__ __launch_bounds__(NT) void k_main(const float* __restrict__ ctx,
                                             const _Float16* __restrict__ Qh,
                                             const _Float16* __restrict__ QTh,
                                             const float* __restrict__ cq,
                                             const float* __restrict__ W,
                                             float* __restrict__ out,
                                             float* __restrict__ pq,
                                             float* __restrict__ KS) {
    __shared__ _Float16 Abuf[BM * 256];     // 64KB, 512B rows, XOR-swizzled
    __shared__ _Float16 Bbuf[2][256 * 64];  // 2 x 32KB, 128B rows, XOR-swizzled
    __shared__ float rowterm[BM];
    __shared__ float m_lds[BM];
    __shared__ float linv_lds[BM];
    __shared__ float eexp[BM];
    __shared__ float redmax[4][BM];
    __shared__ float redsum[4][BM];

    const int t = threadIdx.x;
    const int lane = t & 63, wid = t >> 6;
    const int l31 = lane & 31, lh = lane >> 5;
    const int wr = wid >> 2, wc = wid & 3;
    // XCD-chunked bijective swizzle: each XCD owns 2 whole batches.
    const int bx = blockIdx.x;
    const int blk = (bx & 7) * 32 + (bx >> 3);
    const int n = blk >> 4;   // 16 blocks per batch
    const int blk16 = blk & 15;
    const int c0 = blk16 * BM;

    const _Float16* Qhn = Qh + (size_t)n * LQ * DD;
    const _Float16* QThn = QTh + (size_t)n * DD * LQ;

    auto stageB = [&](int kc, const _Float16* src, int buf) {
#pragma unroll
        for (int j = 0; j < 4; ++j) {
            const int r = wid * 32 + j * 8 + (lane >> 3);
            const int gs = (lane & 7) ^ (r & 7);
            const _Float16* gp = src + (size_t)r * 256 + kc * 64 + gs * 8;
            _Float16* lp = &Bbuf[buf][(wid * 32 + j * 8) * 64];
            GLOAD_LDS16(gp, lp);
        }
    };

    auto gemmChunk = [&](f32x16 (&acc)[2][2], int kcA, int buf) {
#pragma unroll
        for (int kk = 0; kk < 4; ++kk) {
            half8 af[2], bf[2];
#pragma unroll
            for (int mt = 0; mt < 2; ++mt) {
                const int row = 64 * wr + 32 * mt + l31;
                const int kb = kcA * 128 + 32 * kk + 16 * lh;
                af[mt] = *(const half8*)((const char*)Abuf + row * 512 + (kb ^ ((row & 7) << 4)));
            }
#pragma unroll
            for (int nt = 0; nt < 2; ++nt) {
                const int row = 64 * wc + 32 * nt + l31;
                const int kb = 32 * kk + 16 * lh;
                bf[nt] = *(const half8*)((const char*)Bbuf[buf] + row * 128 + (kb ^ ((row & 7) << 4)));
            }
#pragma unroll
            for (int mt = 0; mt < 2; ++mt)
#pragma unroll
                for (int nt = 0; nt < 2; ++nt)
                    acc[mt][nt] = __builtin_amdgcn_mfma_f32_32x32x16_f16(af[mt], bf[nt], acc[mt][nt], 0, 0, 0);
        }
    };

    stageB(0, Qhn, 0);  // async, in flight under A-stage

    // Stage A = ctx*w_m (fp16, swizzled) + rowterm = ctx.w_c
    {
        const int g = t & 31;
        const int r0 = t >> 5;
        float wmv[8], wcv[8];
#pragma unroll
        for (int j = 0; j < 8; ++j) {
            wmv[j] = W[2 * DD + g * 8 + j];
            wcv[j] = W[g * 8 + j];
        }
#pragma unroll
        for (int i = 0; i < 8; ++i) {
            const int r = r0 + 16 * i;
            const float* srcr = ctx + ((size_t)(n * LC + c0 + r)) * DD + g * 8;
            const float4 aa = *(const float4*)srcr;
            const float4 bb = *(const float4*)(srcr + 4);
            const float vals[8] = {aa.x, aa.y, aa.z, aa.w, bb.x, bb.y, bb.z, bb.w};
            half8 cmv;
            float rt = 0.f;
#pragma unroll
            for (int j = 0; j < 8; ++j) {
                cmv[j] = (_Float16)(vals[j] * wmv[j]);
                rt = fmaf(vals[j], wcv[j], rt);
            }
            *(half8*)((char*)Abuf + r * 512 + ((g * 16) ^ ((r & 7) << 4))) = cmv;
#pragma unroll
            for (int o = 16; o > 0; o >>= 1) rt += __shfl_xor(rt, o, 64);
            if (g == 0) rowterm[r] = rt;
        }
    }
    __syncthreads();  // A + B0 ready

    // GEMM1: S = CM @ Q^T
    f32x16 acc[2][2] = {};
#pragma unroll
    for (int kc = 0; kc < 4; ++kc) {
        if (kc) __syncthreads();
        if (kc < 3) stageB(kc + 1, Qhn, (kc + 1) & 1);
        else stageB(0, QThn, 0);  // prefetch GEMM2 chunk 0
        gemmChunk(acc, kc, kc & 1);
    }
    __syncthreads();  // S1

    float cqv[2];
    cqv[0] = cq[n * LQ + 64 * wc + l31];
    cqv[1] = cq[n * LQ + 64 * wc + 32 + l31];

    // s = acc + rowterm + cq; per-row max
#pragma unroll
    for (int mt = 0; mt < 2; ++mt) {
#pragma unroll
        for (int r = 0; r < 16; ++r) {
            const int rl = 64 * wr + 32 * mt + (r & 3) + 8 * (r >> 2) + 4 * lh;
            const float rterm = rowterm[rl];
            const float v0 = acc[mt][0][r] + rterm + cqv[0];
            const float v1 = acc[mt][1][r] + rterm + cqv[1];
            acc[mt][0][r] = v0;
            acc[mt][1][r] = v1;
            float mx = fmaxf(v0, v1);
#pragma unroll
            for (int o = 16; o > 0; o >>= 1) mx = fmaxf(mx, __shfl_xor(mx, o, 64));
            if (l31 == 0) redmax[wc][rl] = mx;
        }
    }
    __syncthreads();  // S2
    if (t < BM)
        m_lds[t] = fmaxf(fmaxf(redmax[0][t], redmax[1][t]), fmaxf(redmax[2][t], redmax[3][t]));
    __syncthreads();  // S3

    // waves 0,1: per-64-row q2c partial stats
    if (t < BM) {
        const float mv = m_lds[t];
        const float kb = waveReduceMax(mv);
        const float e = __expf(mv - kb);
        eexp[t] = e;
        const float sb = waveReduceSum(e);
        if (lane == 0) {
            KS[(n * 32 + blk16 * 2 + (t >> 6)) * 2 + 0] = kb;
            KS[(n * 32 + blk16 * 2 + (t >> 6)) * 2 + 1] = sb;
        }
    }

    // p = exp(s - m); row sums; store P (unnormalized fp16) into Abuf
#pragma unroll
    for (int mt = 0; mt < 2; ++mt) {
#pragma unroll
        for (int r = 0; r < 16; ++r) {
            const int rl = 64 * wr + 32 * mt + (r & 3) + 8 * (r >> 2) + 4 * lh;
            const float mrow = m_lds[rl];
            const float p0 = __expf(acc[mt][0][r] - mrow);
            const float p1 = __expf(acc[mt][1][r] - mrow);
            const int q0 = 64 * wc + l31, q1 = q0 + 32;
            *((_Float16*)((char*)Abuf + rl * 512 + ((q0 * 2) ^ ((rl & 7) << 4)))) = (_Float16)p0;
            *((_Float16*)((char*)Abuf + rl * 512 + ((q1 * 2) ^ ((rl & 7) << 4)))) = (_Float16)p1;
            float sm = p0 + p1;
#pragma unroll
            for (int o = 16; o > 0; o >>= 1) sm += __shfl_xor(sm, o, 64);
            if (l31 == 0) redsum[wc][rl] = sm;
        }
    }
    __syncthreads();  // S4
    if (t < BM)
        linv_lds[t] = 1.0f / (redsum[0][t] + redsum[1][t] + redsum[2][t] + redsum[3][t]);
    __syncthreads();  // S5

    // GEMM2: c2q = P @ Q
    f32x16 acc2[2][2] = {};
#pragma unroll
    for (int kc = 0; kc < 4; ++kc) {
        if (kc) __syncthreads();
        if (kc < 3) stageB(kc + 1, QThn, (kc + 1) & 1);
        gemmChunk(acc2, kc, kc & 1);
    }

    // epilogue: G parts 1,2 (non-temporal) + q2c partial accumulation
    float pqa[2] = {0.f, 0.f};
#pragma unroll
    for (int mt = 0; mt < 2; ++mt) {
#pragma unroll
        for (int nt = 0; nt < 2; ++nt) {
            const int col = 64 * wc + 32 * nt + l31;
#pragma unroll
            for (int r = 0; r < 16; ++r) {
                const int rl = 64 * wr + 32 * mt + (r & 3) + 8 * (r >> 2) + 4 * lh;
                const size_t gc = (size_t)(n * LC + c0 + rl);
                const float li = linv_lds[rl];
                const float cv = ctx[gc * DD + col];
                const float ov = acc2[mt][nt][r] * li;
                const size_t ob = gc * 1024 + col;
                __builtin_nontemporal_store(ov, &out[ob + 256]);
                __builtin_nontemporal_store(cv * ov, &out[ob + 512]);
                pqa[nt] = fmaf(eexp[rl], cv, pqa[nt]);
            }
        }
    }
#pragma unroll
    for (int nt = 0; nt < 2; ++nt) {
        pqa[nt] += __shfl_xor(pqa[nt], 32, 64);
        if (lh == 0) {
            const int col = 64 * wc + 32 * nt + l31;
            pq[((size_t)(n * 32 + blk16 * 2 + wr)) * 256 + col] = pqa[nt];
        }
    }
}

// Tail: combine per-batch partials -> q2c; write parts 0 and 3 (both from the
// same ctx float4 load).
__global__ __launch_bounds__(256) void k_tail(const float* __restrict__ ctx,
                                              const float* __restrict__ pq,
                                              const float* __restrict__ KS,
                                              float* __restrict__ out) {
    // XCD-chunked swizzle aligned with k_main's batch->XCD mapping.
    const int bx = blockIdx.x;
    const int blk = (bx & 7) * 64 + (bx >> 3);
    const int n = blk >> 5;
    const int c0 = (blk & 31) * 64;
    const int t = threadIdx.x;
    const int cg = t & 63;   // cols 4cg..4cg+3
    const int rs = t >> 6;   // rows rs*16..rs*16+15

    float bmax = -1e30f;
#pragma unroll
    for (int b = 0; b < 32; ++b) bmax = fmaxf(bmax, KS[(n * 32 + b) * 2]);
    float Z = 0.f;
    float4 a = {0.f, 0.f, 0.f, 0.f};
#pragma unroll
    for (int b = 0; b < 32; ++b) {
        const float w = __expf(KS[(n * 32 + b) * 2] - bmax);
        Z = fmaf(w, KS[(n * 32 + b) * 2 + 1], Z);
        const float4 p4 = *(const float4*)&pq[((size_t)(n * 32 + b)) * 256 + cg * 4];
        a.x = fmaf(w, p4.x, a.x);
        a.y = fmaf(w, p4.y, a.y);
        a.z = fmaf(w, p4.z, a.z);
        a.w = fmaf(w, p4.w, a.w);
    }
    const float zi = 1.0f / Z;
    const float4 q2c4 = {a.x * zi, a.y * zi, a.z * zi, a.w * zi};

#pragma unroll
    for (int r = 0; r < 16; ++r) {
        const size_t gc = (size_t)(n * LC + c0 + rs * 16 + r);
        const float4 cv = *(const float4*)&ctx[gc * DD + cg * 4];
        f32x4 c4;
        c4.x = cv.x; c4.y = cv.y; c4.z = cv.z; c4.w = cv.w;
        f32x4 ov;
        ov.x = cv.x * q2c4.x;
        ov.y = cv.y * q2c4.y;
        ov.z = cv.z * q2c4.z;
        ov.w = cv.w * q2c4.w;
        __builtin_nontemporal_store(c4, (f32x4*)&out[gc * 1024 + cg * 4]);
        __builtin_nontemporal_store(ov, (f32x4*)&out[gc * 1024 + 768 + cg * 4]);
    }
}

extern "C" void kernel_launch(void* const* d_in, const int* in_sizes, int n_in,
                              void* d_out, int out_size, void* d_ws, size_t ws_size,
                              hipStream_t stream) {
    const float* ctx = (const float*)d_in[0];  // (16,2048,256)
    const float* q = (const float*)d_in[1];    // (16,256,256)
    const float* W = (const float*)d_in[2];    // (768,)
    float* out = (float*)d_out;                // (16,2048,1024)

    _Float16* Qh = (_Float16*)d_ws;                    // 2 MB
    _Float16* QTh = Qh + (size_t)BN * LQ * DD;         // 2 MB
    float* fws = (float*)(QTh + (size_t)BN * DD * LQ);
    float* cq = fws;                  // 4096
    float* pq = cq + BN * LQ;         // 16*32*256 = 131072
    float* KS = pq + BN * 32 * 256;   // 1024

    k_prep<<<dim3(LQ / 32, BN), 256, 0, stream>>>(q, W, Qh, QTh, cq);
    k_main<<<BN * LC / BM, NT, 0, stream>>>(ctx, Qh, QTh, cq, W, out, pq, KS);
    k_tail<<<BN * LC / 64, 256, 0, stream>>>(ctx, pq, KS, out);
}